// Round 3
// baseline (583.182 us; speedup 1.0000x reference)
//
#include <hip/hip_runtime.h>
#include <hip/hip_bf16.h>

#define NN 50000
#define EE 800000
#define DD 64
#define HH 128

typedef __attribute__((ext_vector_type(8))) short bf16x8;
typedef __attribute__((ext_vector_type(4))) float f32x4;

__device__ __forceinline__ short f2bf(float f) {
  union { __hip_bfloat16 h; short s; } u;
  u.h = __float2bfloat16(f);
  return u.s;
}

// Load 8 consecutive fp32 elements, round to bf16x8 (MFMA operand).
__device__ __forceinline__ bf16x8 load8(const float* p) {
  const f32x4* s = (const f32x4*)p;
  f32x4 a = s[0], b = s[1];
  bf16x8 v;
  v[0] = f2bf(a[0]); v[1] = f2bf(a[1]); v[2] = f2bf(a[2]); v[3] = f2bf(a[3]);
  v[4] = f2bf(b[0]); v[5] = f2bf(b[1]); v[6] = f2bf(b[2]); v[7] = f2bf(b[3]);
  return v;
}

// -------------------- Edge block --------------------
// Per 64-edge tile: X[64x192] = [edge_feats | nf[send] | nf[recv]] (bf16 in LDS)
// H = relu(X @ We1 + be1)  [64x128]
// e = H @ We2 + be2        [64x64] -> e_out (fp32) + fp32 atomic scatter to agg
// Weights in registers (loop-invariant B-fragments). LDS strides 200/136
// (rows = 4 dwords mod 32 banks -> 2-way alias = free per m136).
__global__ __launch_bounds__(256, 3)
void edge_kernel(const float* __restrict__ node_feats,
                 const float* __restrict__ edge_feats,
                 const float* __restrict__ We1,   // [192][128]
                 const float* __restrict__ be1,   // [128]
                 const float* __restrict__ We2,   // [128][64]
                 const float* __restrict__ be2,   // [64]
                 const int* __restrict__ senders,
                 const int* __restrict__ receivers,
                 float* __restrict__ e_out,       // [E][64] fp32
                 float* __restrict__ agg)         // [N][64] fp32 (zeroed)
{
  __shared__ short Xs[64 * 200];
  __shared__ short Hs[64 * 136];
  __shared__ int sid[64];
  __shared__ int rid[64];

  const int tid  = threadIdx.x;
  const int lane = tid & 63;
  const int wave = tid >> 6;
  const int qu   = lane >> 4;   // quad 0..3
  const int l16  = lane & 15;

  // ---- loop-invariant weight fragments (B-operand: n = l16, k = qu*8+j) ----
  bf16x8 w1[2][6];
#pragma unroll
  for (int ct = 0; ct < 2; ct++) {
    const int n = wave * 32 + ct * 16 + l16;
#pragma unroll
    for (int kk = 0; kk < 6; kk++) {
      bf16x8 v;
#pragma unroll
      for (int j = 0; j < 8; j++) v[j] = f2bf(We1[(kk * 32 + qu * 8 + j) * HH + n]);
      w1[ct][kk] = v;
    }
  }
  bf16x8 w2[4];
  {
    const int n = wave * 16 + l16;
#pragma unroll
    for (int kk = 0; kk < 4; kk++) {
      bf16x8 v;
#pragma unroll
      for (int j = 0; j < 8; j++) v[j] = f2bf(We2[(kk * 32 + qu * 8 + j) * DD + n]);
      w2[kk] = v;
    }
  }
  const float b1a = be1[wave * 32 + l16];
  const float b1b = be1[wave * 32 + 16 + l16];
  const float b2  = be2[wave * 16 + l16];

  for (int tile = blockIdx.x; tile < EE / 64; tile += gridDim.x) {
    const int ebase = tile * 64;
    __syncthreads();  // prior iter's rid/Hs readers done before overwrite
    if (tid < 64)       sid[tid]      = senders[ebase + tid];
    else if (tid < 128) rid[tid - 64] = receivers[ebase + (tid - 64)];
    __syncthreads();

    // stage X: 64 rows x 24 chunks of 8 elems; 6 chunks/thread
#pragma unroll
    for (int i = 0; i < 6; i++) {
      int cid = tid + i * 256;        // 0..1535
      int r = cid / 24, c = cid % 24;
      const float* src;
      if (c < 8)       src = edge_feats + (size_t)(ebase + r) * DD + c * 8;
      else if (c < 16) src = node_feats + (size_t)sid[r] * DD + (c - 8) * 8;
      else             src = node_feats + (size_t)rid[r] * DD + (c - 16) * 8;
      *(bf16x8*)&Xs[r * 200 + c * 8] = load8(src);
    }
    __syncthreads();

    // ---- layer 1: [64x192] @ [192x(32 per wave)] ----
    f32x4 acc[4][2];
#pragma unroll
    for (int rt = 0; rt < 4; rt++)
#pragma unroll
      for (int ct = 0; ct < 2; ct++) acc[rt][ct] = (f32x4){0.f, 0.f, 0.f, 0.f};

#pragma unroll
    for (int kk = 0; kk < 6; kk++) {
      bf16x8 a[4];
#pragma unroll
      for (int rt = 0; rt < 4; rt++)
        a[rt] = *(const bf16x8*)&Xs[(rt * 16 + l16) * 200 + kk * 32 + qu * 8];
#pragma unroll
      for (int rt = 0; rt < 4; rt++)
#pragma unroll
        for (int ct = 0; ct < 2; ct++)
          acc[rt][ct] = __builtin_amdgcn_mfma_f32_16x16x32_bf16(
              a[rt], w1[ct][kk], acc[rt][ct], 0, 0, 0);
    }

    // bias + relu -> Hs (bf16); C/D layout: row = rt*16+qu*4+r, col = n
#pragma unroll
    for (int rt = 0; rt < 4; rt++)
#pragma unroll
      for (int ct = 0; ct < 2; ct++)
#pragma unroll
        for (int r = 0; r < 4; r++) {
          float v = acc[rt][ct][r] + (ct ? b1b : b1a);
          v = v > 0.f ? v : 0.f;
          Hs[(rt * 16 + qu * 4 + r) * 136 + wave * 32 + ct * 16 + l16] = f2bf(v);
        }
    __syncthreads();

    // ---- layer 2: [64x128] @ [128x(16 per wave)] ----
    f32x4 acc2[4];
#pragma unroll
    for (int rt = 0; rt < 4; rt++) acc2[rt] = (f32x4){0.f, 0.f, 0.f, 0.f};
#pragma unroll
    for (int kk = 0; kk < 4; kk++) {
#pragma unroll
      for (int rt = 0; rt < 4; rt++) {
        bf16x8 a = *(const bf16x8*)&Hs[(rt * 16 + l16) * 136 + kk * 32 + qu * 8];
        acc2[rt] = __builtin_amdgcn_mfma_f32_16x16x32_bf16(a, w2[kk], acc2[rt], 0, 0, 0);
      }
    }

    // epilogue: write e (fp32) + scatter-add fp32 into agg
    const int col = wave * 16 + l16;
#pragma unroll
    for (int rt = 0; rt < 4; rt++)
#pragma unroll
      for (int r = 0; r < 4; r++) {
        int row = rt * 16 + qu * 4 + r;
        float v = acc2[rt][r] + b2;
        e_out[(size_t)(ebase + row) * DD + col] = v;
        atomicAdd(&agg[(size_t)rid[row] * DD + col], v);
      }
  }
}

// -------------------- Node block --------------------
// Per 64-node tile: X[64x128] = [bf16(agg) | node_feats]
// n = relu(X @ Wn1 + bn1) @ Wn2 + bn2  -> n_out (fp32)
__global__ __launch_bounds__(256, 3)
void node_kernel(const float* __restrict__ node_feats,
                 const float* __restrict__ agg,
                 const float* __restrict__ Wn1,   // [128][128]
                 const float* __restrict__ bn1,   // [128]
                 const float* __restrict__ Wn2,   // [128][64]
                 const float* __restrict__ bn2,   // [64]
                 float* __restrict__ n_out)       // [N][64] fp32
{
  __shared__ short Xs[64 * 136];
  __shared__ short Hs[64 * 136];

  const int tid  = threadIdx.x;
  const int lane = tid & 63;
  const int wave = tid >> 6;
  const int qu   = lane >> 4;
  const int l16  = lane & 15;

  bf16x8 w1[2][4];
#pragma unroll
  for (int ct = 0; ct < 2; ct++) {
    const int n = wave * 32 + ct * 16 + l16;
#pragma unroll
    for (int kk = 0; kk < 4; kk++) {
      bf16x8 v;
#pragma unroll
      for (int j = 0; j < 8; j++) v[j] = f2bf(Wn1[(kk * 32 + qu * 8 + j) * HH + n]);
      w1[ct][kk] = v;
    }
  }
  bf16x8 w2[4];
  {
    const int n = wave * 16 + l16;
#pragma unroll
    for (int kk = 0; kk < 4; kk++) {
      bf16x8 v;
#pragma unroll
      for (int j = 0; j < 8; j++) v[j] = f2bf(Wn2[(kk * 32 + qu * 8 + j) * DD + n]);
      w2[kk] = v;
    }
  }
  const float b1a = bn1[wave * 32 + l16];
  const float b1b = bn1[wave * 32 + 16 + l16];
  const float b2  = bn2[wave * 16 + l16];

  const int nbase = blockIdx.x * 64;

  // stage X: 64 rows x 16 chunks of 8 elems; 4 chunks/thread
#pragma unroll
  for (int i = 0; i < 4; i++) {
    int cid = tid + i * 256;          // 0..1023
    int r = cid >> 4, c = cid & 15;
    int node = nbase + r;
    bf16x8 v;
    if (node < NN) {
      if (c < 8) v = load8(agg + (size_t)node * DD + c * 8);
      else       v = load8(node_feats + (size_t)node * DD + (c - 8) * 8);
    } else {
      v = (bf16x8){0, 0, 0, 0, 0, 0, 0, 0};
    }
    *(bf16x8*)&Xs[r * 136 + c * 8] = v;
  }
  __syncthreads();

  f32x4 acc[4][2];
#pragma unroll
  for (int rt = 0; rt < 4; rt++)
#pragma unroll
    for (int ct = 0; ct < 2; ct++) acc[rt][ct] = (f32x4){0.f, 0.f, 0.f, 0.f};

#pragma unroll
  for (int kk = 0; kk < 4; kk++) {
    bf16x8 a[4];
#pragma unroll
    for (int rt = 0; rt < 4; rt++)
      a[rt] = *(const bf16x8*)&Xs[(rt * 16 + l16) * 136 + kk * 32 + qu * 8];
#pragma unroll
    for (int rt = 0; rt < 4; rt++)
#pragma unroll
      for (int ct = 0; ct < 2; ct++)
        acc[rt][ct] = __builtin_amdgcn_mfma_f32_16x16x32_bf16(
            a[rt], w1[ct][kk], acc[rt][ct], 0, 0, 0);
  }

#pragma unroll
  for (int rt = 0; rt < 4; rt++)
#pragma unroll
    for (int ct = 0; ct < 2; ct++)
#pragma unroll
      for (int r = 0; r < 4; r++) {
        float v = acc[rt][ct][r] + (ct ? b1b : b1a);
        v = v > 0.f ? v : 0.f;
        Hs[(rt * 16 + qu * 4 + r) * 136 + wave * 32 + ct * 16 + l16] = f2bf(v);
      }
  __syncthreads();

  f32x4 acc2[4];
#pragma unroll
  for (int rt = 0; rt < 4; rt++) acc2[rt] = (f32x4){0.f, 0.f, 0.f, 0.f};
#pragma unroll
  for (int kk = 0; kk < 4; kk++) {
#pragma unroll
    for (int rt = 0; rt < 4; rt++) {
      bf16x8 a = *(const bf16x8*)&Hs[(rt * 16 + l16) * 136 + kk * 32 + qu * 8];
      acc2[rt] = __builtin_amdgcn_mfma_f32_16x16x32_bf16(a, w2[kk], acc2[rt], 0, 0, 0);
    }
  }

  const int col = wave * 16 + l16;
#pragma unroll
  for (int rt = 0; rt < 4; rt++)
#pragma unroll
    for (int r = 0; r < 4; r++) {
      int row  = rt * 16 + qu * 4 + r;
      int node = nbase + row;
      if (node < NN) {
        n_out[(size_t)node * DD + col] = acc2[rt][r] + b2;
      }
    }
}

extern "C" void kernel_launch(void* const* d_in, const int* in_sizes, int n_in,
                              void* d_out, int out_size, void* d_ws, size_t ws_size,
                              hipStream_t stream) {
  const float* node_feats = (const float*)d_in[0];
  const float* edge_feats = (const float*)d_in[1];
  const float* We1 = (const float*)d_in[2];
  const float* be1 = (const float*)d_in[3];
  const float* We2 = (const float*)d_in[4];
  const float* be2 = (const float*)d_in[5];
  const float* Wn1 = (const float*)d_in[6];
  const float* bn1 = (const float*)d_in[7];
  const float* Wn2 = (const float*)d_in[8];
  const float* bn2 = (const float*)d_in[9];
  const int* senders   = (const int*)d_in[10];
  const int* receivers = (const int*)d_in[11];

  float* e_out = (float*)d_out;                  // [E][64] fp32
  float* n_out = e_out + (size_t)EE * DD;        // [N][64] fp32
  float* agg = (float*)d_ws;                     // [N][64] fp32 accumulator

  hipMemsetAsync(agg, 0, (size_t)NN * DD * sizeof(float), stream);
  edge_kernel<<<768, 256, 0, stream>>>(node_feats, edge_feats, We1, be1, We2, be2,
                                       senders, receivers, e_out, agg);
  node_kernel<<<(NN + 63) / 64, 256, 0, stream>>>(node_feats, agg, Wn1, bn1, Wn2,
                                                  bn2, n_out);
}